// Round 2
// 2285.988 us; speedup vs baseline: 1.5762x; 1.5762x over previous
//
#include <hip/hip_runtime.h>
#include <hip/hip_bf16.h>
#include <math.h>

// Problem constants
#define BATCH 4
#define CDIM 192
#define HDIM 224
#define WDIM 224
#define HWSZ (HDIM * WDIM)            // 50176
#define NWH 28                        // 224/8
#define NWIN (BATCH * NWH * NWH)      // 3136
#define TOK 64
#define MTOK (NWIN * TOK)             // 200704
#define HEADS 6
#define C3 (3 * CDIM)                 // 576
#define C4 (4 * CDIM)                 // 768
#define IMGSZ (BATCH * CDIM * HWSZ)   // 38535168
#define ATTN_SCALE 0.17677669529663687f
#define LN_EPS 1e-6f

typedef __attribute__((ext_vector_type(8))) short bfrag;   // 8 bf16 (4 VGPRs)
typedef __attribute__((ext_vector_type(4))) float f32x4;

__device__ __forceinline__ float bf2f(unsigned short u) {
    union { unsigned int i; float f; } v; v.i = ((unsigned int)u) << 16; return v.f;
}
__device__ __forceinline__ unsigned short f2bf(float f) {
    union { unsigned int i; float f; } v; v.f = f;
    unsigned int r = (v.i + 0x7FFFu + ((v.i >> 16) & 1u)) >> 16;   // RNE
    return (unsigned short)r;
}
// exact-erf GELU via Abramowitz-Stegun 7.1.26 (|erf err| <= 1.5e-7)
__device__ __forceinline__ float gelu_erf(float x) {
    float z = fabsf(x) * 0.70710678118654752f;
    float t = __fdividef(1.0f, 1.0f + 0.3275911f * z);
    float poly = t * (0.254829592f + t * (-0.284496736f +
                 t * (1.421413741f + t * (-1.453152027f + t * 1.061405429f))));
    float erfv = 1.0f - poly * __expf(-z * z);
    erfv = (x < 0.f) ? -erfv : erfv;
    return 0.5f * x * (1.0f + erfv);
}

// ---------------------------------------------------------------------------
// Prep: transpose+convert weights to bf16 (n-major, k-contiguous) once/launch.
// WqkvT is the full 576x192 (Q rows 0..192, K rows 192..384, V rows 384..576).
__launch_bounds__(256)
__global__ void prep_weights_kernel(const float* __restrict__ w_qkv,
                                    const float* __restrict__ w_g1,
                                    const float* __restrict__ w_g2,
                                    ushort* __restrict__ WqkvT,
                                    ushort* __restrict__ W1T,
                                    ushort* __restrict__ W2T) {
    int idx = blockIdx.x * 256 + threadIdx.x;
    if (idx < 576 * 192) {
        int n = idx / 192, k = idx % 192;
        WqkvT[idx] = f2bf(w_qkv[(size_t)k * C3 + n]);
    }
    if (idx < 768 * 192) {
        int n = idx / 192, k = idx % 192;
        W1T[idx] = f2bf(w_g1[(size_t)k * C4 + n]);
    }
    if (idx < 192 * 768) {
        int n = idx / 768, k = idx % 768;
        W2T[idx] = f2bf(w_g2[(size_t)k * CDIM + n]);
    }
}

// ---------------------------------------------------------------------------
// K1: 1x1 conv == per-batch GEMM (fp32)
__launch_bounds__(256)
__global__ void conv1x1_kernel(const float* __restrict__ x,
                               const float* __restrict__ w1,
                               const float* __restrict__ b1,
                               float* __restrict__ f1) {
    __shared__ __align__(16) float As[16][68];
    __shared__ __align__(16) float Bs[16][64];
    const int tid = threadIdx.x;
    const int p0 = blockIdx.x * 64;
    const int m0 = blockIdx.y * 64;
    const int b  = blockIdx.z;
    const int tm = tid >> 4, tn = tid & 15;
    const int mload = tid >> 2, kload = (tid & 3) * 4;
    const int kw = tid >> 4, nw = (tid & 15) * 4;
    float acc[4][4] = {};
    const float* xb = x + (size_t)b * CDIM * HWSZ;
    for (int k0 = 0; k0 < CDIM; k0 += 16) {
        float4 av = *(const float4*)&w1[(size_t)(m0 + mload) * CDIM + k0 + kload];
        float4 bv = *(const float4*)&xb[(size_t)(k0 + kw) * HWSZ + p0 + nw];
        __syncthreads();
        As[kload + 0][mload] = av.x;
        As[kload + 1][mload] = av.y;
        As[kload + 2][mload] = av.z;
        As[kload + 3][mload] = av.w;
        *(float4*)&Bs[kw][nw] = bv;
        __syncthreads();
#pragma unroll
        for (int kk = 0; kk < 16; ++kk) {
            float a[4], bb[4];
            *(float4*)a  = *(const float4*)&As[kk][tm * 4];
            *(float4*)bb = *(const float4*)&Bs[kk][tn * 4];
#pragma unroll
            for (int i = 0; i < 4; ++i)
#pragma unroll
                for (int j = 0; j < 4; ++j) acc[i][j] += a[i] * bb[j];
        }
    }
    float* outb = f1 + (size_t)b * CDIM * HWSZ;
#pragma unroll
    for (int i = 0; i < 4; ++i) {
        int m = m0 + tm * 4 + i;
        float bias = b1[m];
        float4 o = make_float4(acc[i][0] + bias, acc[i][1] + bias,
                               acc[i][2] + bias, acc[i][3] + bias);
        *(float4*)&outb[(size_t)m * HWSZ + p0 + tn * 4] = o;
    }
}

// ---------------------------------------------------------------------------
// K2: depthwise 3x3 SAME, NCHW.
__launch_bounds__(256)
__global__ void dwconv_kernel(const float* __restrict__ f1,
                              const float* __restrict__ w_dw,
                              const float* __restrict__ b_dw,
                              float* __restrict__ f2) {
    unsigned int idx = blockIdx.x * 256u + threadIdx.x;
    int w = idx % WDIM;
    unsigned int r = idx / WDIM;
    int h = r % HDIM;
    unsigned int bc = r / HDIM;
    int c = bc % CDIM;
    const float* base = f1 + (size_t)bc * HWSZ;
    const float* wd = w_dw + c * 9;
    float acc = b_dw[c];
#pragma unroll
    for (int ky = 0; ky < 3; ++ky) {
        int hy = h + ky - 1;
        if (hy < 0 || hy >= HDIM) continue;
#pragma unroll
        for (int kx = 0; kx < 3; ++kx) {
            int wx = w + kx - 1;
            if (wx < 0 || wx >= WDIM) continue;
            acc += base[hy * WDIM + wx] * wd[ky * 3 + kx];
        }
    }
    f2[idx] = acc;
}

// ---------------------------------------------------------------------------
// K3: LayerNorm over C + window partition -> token-major pb[M][192] (bf16).
__launch_bounds__(256)
__global__ void ln_part_kernel(const float* __restrict__ f2,
                               const float* __restrict__ ln_g,
                               const float* __restrict__ ln_b,
                               ushort* __restrict__ pb) {
    __shared__ float T[CDIM][33];
    __shared__ float Rs[8][32], Rs2[8][32];
    __shared__ float Mu[32], Rsig[32];
    const int tid = threadIdx.x;
    const int wt = blockIdx.x, h = blockIdx.y, b = blockIdx.z;
    const int w0 = wt * 32;
    const size_t rowbase = (size_t)b * CDIM * HWSZ + (size_t)h * WDIM + w0;
    for (int idx = tid; idx < CDIM * 32; idx += 256) {
        int c = idx >> 5, j = idx & 31;
        T[c][j] = f2[rowbase + (size_t)c * HWSZ + j];
    }
    __syncthreads();
    {
        int j = tid & 31, q = tid >> 5;
        float s = 0.f, s2 = 0.f;
#pragma unroll
        for (int i = 0; i < 24; ++i) {
            float v = T[q * 24 + i][j];
            s += v; s2 += v * v;
        }
        Rs[q][j] = s; Rs2[q][j] = s2;
    }
    __syncthreads();
    if (tid < 32) {
        float s = 0.f, s2 = 0.f;
#pragma unroll
        for (int q = 0; q < 8; ++q) { s += Rs[q][tid]; s2 += Rs2[q][tid]; }
        float mu = s * (1.0f / CDIM);
        float var = s2 * (1.0f / CDIM) - mu * mu;
        Mu[tid] = mu;
        Rsig[tid] = rsqrtf(var + LN_EPS);
    }
    __syncthreads();
    const int l = tid & 63;
    const int jo = tid >> 6;
    for (int it = 0; it < 8; ++it) {
        int j = it * 4 + jo;
        int w = w0 + j;
        size_t token = ((size_t)(b * NWH + (h >> 3)) * NWH + (w >> 3)) * TOK
                       + ((h & 7) * 8 + (w & 7));
        float mu = Mu[j], rs = Rsig[j];
#pragma unroll
        for (int rep = 0; rep < 3; ++rep) {
            int c = l + rep * 64;
            pb[token * CDIM + c] = f2bf((T[c][j] - mu) * rs * ln_g[c] + ln_b[c]);
        }
    }
}

// ---------------------------------------------------------------------------
// K4: MFMA attention. 1 window (64 tokens) per block, 4 waves.
// Per head: QKV GEMM (64x96, K=192, B-frags direct from global bf16 WqkvT),
// S = Q.K^T (MFMA, K=32), in-register softmax (16-lane shfl reduce),
// O = P.V^T (MFMA, K=64) -> oa fp32.
__launch_bounds__(256)
__global__ void attn_mfma_kernel(const ushort* __restrict__ pb,
                                 const ushort* __restrict__ WqkvT,
                                 const float* __restrict__ b_qkv,
                                 float* __restrict__ oa) {
    __shared__ __align__(16) ushort Pt[64 * 200];    // 25600 B p tile, k-contig
    __shared__ __align__(16) ushort Qb[64 * 40];     //  5120 B Q (scale folded)
    __shared__ __align__(16) ushort Kb[64 * 40];     //  5120 B K
    __shared__ __align__(16) ushort Vt[32 * 72];     //  4608 B V^T (d rows, token-contig)
    __shared__ __align__(16) ushort Pbf[64 * 72];    //  9216 B softmax(P) bf16
    const int tid = threadIdx.x;
    const int lane = tid & 63, wave = tid >> 6;
    const int quad = lane >> 4, l16 = lane & 15;
    const int m0 = wave * 16;
    const size_t tok0 = (size_t)blockIdx.x * 64;

    // stage p tile (bf16 passthrough), 16B chunks
    for (int idx = tid * 8; idx < 64 * 192; idx += 2048) {
        int r = idx / 192, c = idx % 192;
        *(uint4*)&Pt[r * 200 + c] = *(const uint4*)&pb[(tok0 + r) * 192 + c];
    }
    __syncthreads();

    for (int h = 0; h < HEADS; ++h) {
        // ---- QKV GEMM for this head: rows m0..m0+16 x 96 cols (Q|K|V) ----
        f32x4 acc[6];
#pragma unroll
        for (int t = 0; t < 6; ++t) acc[t] = (f32x4){0.f, 0.f, 0.f, 0.f};
#pragma unroll
        for (int kk = 0; kk < 6; ++kk) {
            bfrag a = *(const bfrag*)&Pt[(m0 + l16) * 200 + kk * 32 + quad * 8];
#pragma unroll
            for (int t = 0; t < 6; ++t) {
                const int nrow = (t < 2) ? (h * 32 + t * 16 + l16)
                               : (t < 4) ? (192 + h * 32 + (t - 2) * 16 + l16)
                                         : (384 + h * 32 + (t - 4) * 16 + l16);
                bfrag b = *(const bfrag*)&WqkvT[(size_t)nrow * 192 + kk * 32 + quad * 8];
                acc[t] = __builtin_amdgcn_mfma_f32_16x16x32_bf16(a, b, acc[t], 0, 0, 0);
            }
        }
        // write Q (scale folded), K, V^T to LDS
#pragma unroll
        for (int t = 0; t < 2; ++t) {
            float bq = b_qkv[h * 32 + t * 16 + l16];
            float bk = b_qkv[192 + h * 32 + t * 16 + l16];
            float bv = b_qkv[384 + h * 32 + t * 16 + l16];
#pragma unroll
            for (int reg = 0; reg < 4; ++reg) {
                int row = m0 + quad * 4 + reg;
                Qb[row * 40 + t * 16 + l16] = f2bf((acc[t][reg] + bq) * ATTN_SCALE);
                Kb[row * 40 + t * 16 + l16] = f2bf(acc[t + 2][reg] + bk);
                Vt[(t * 16 + l16) * 72 + row] = f2bf(acc[t + 4][reg] + bv);
            }
        }
        __syncthreads();

        // ---- S = Q.K^T (64x64, K=32): 4 col-tiles, 1 MFMA each ----
        f32x4 s[4];
        {
            bfrag aq = *(const bfrag*)&Qb[(m0 + l16) * 40 + quad * 8];
#pragma unroll
            for (int t = 0; t < 4; ++t) {
                bfrag b = *(const bfrag*)&Kb[(t * 16 + l16) * 40 + quad * 8];
                s[t] = __builtin_amdgcn_mfma_f32_16x16x32_bf16(
                    aq, b, (f32x4){0.f, 0.f, 0.f, 0.f}, 0, 0, 0);
            }
        }
        // ---- softmax per row (row = m0+quad*4+reg; 64 cols in 16 lanes x 4 tiles)
#pragma unroll
        for (int reg = 0; reg < 4; ++reg) {
            float mx = fmaxf(fmaxf(s[0][reg], s[1][reg]), fmaxf(s[2][reg], s[3][reg]));
            mx = fmaxf(mx, __shfl_xor(mx, 1));
            mx = fmaxf(mx, __shfl_xor(mx, 2));
            mx = fmaxf(mx, __shfl_xor(mx, 4));
            mx = fmaxf(mx, __shfl_xor(mx, 8));
            float e[4], sum = 0.f;
#pragma unroll
            for (int t = 0; t < 4; ++t) { e[t] = __expf(s[t][reg] - mx); sum += e[t]; }
            sum += __shfl_xor(sum, 1);
            sum += __shfl_xor(sum, 2);
            sum += __shfl_xor(sum, 4);
            sum += __shfl_xor(sum, 8);
            float inv = 1.0f / sum;
            int row = m0 + quad * 4 + reg;
#pragma unroll
            for (int t = 0; t < 4; ++t)
                Pbf[row * 72 + t * 16 + l16] = f2bf(e[t] * inv);
        }
        __syncthreads();

        // ---- O = P.V (64x32, K=64): 2 col-tiles x 2 k-steps ----
        f32x4 o[2];
        o[0] = (f32x4){0.f, 0.f, 0.f, 0.f};
        o[1] = (f32x4){0.f, 0.f, 0.f, 0.f};
#pragma unroll
        for (int kk = 0; kk < 2; ++kk) {
            bfrag a = *(const bfrag*)&Pbf[(m0 + l16) * 72 + kk * 32 + quad * 8];
#pragma unroll
            for (int t = 0; t < 2; ++t) {
                bfrag b = *(const bfrag*)&Vt[(t * 16 + l16) * 72 + kk * 32 + quad * 8];
                o[t] = __builtin_amdgcn_mfma_f32_16x16x32_bf16(a, b, o[t], 0, 0, 0);
            }
        }
#pragma unroll
        for (int t = 0; t < 2; ++t) {
            int col = h * 32 + t * 16 + l16;
#pragma unroll
            for (int reg = 0; reg < 4; ++reg) {
                int row = m0 + quad * 4 + reg;
                oa[(tok0 + row) * (size_t)CDIM + col] = o[t][reg];
            }
        }
        __syncthreads();   // protect Qb/Kb/Vt/Pbf before next head's writes
    }
}

// ---------------------------------------------------------------------------
// K5: MFMA GMLP. Block = 64 tokens, 4 waves. v = p@Wv+b (MFMA, K=192);
// hidden in 12 chunks of 64: GEMM1 -> gelu(bf16 H in LDS) -> GEMM2 acc.
// Epilogue: a_io *= (g + b_g2)  (product with attention output, in place).
__launch_bounds__(256)
__global__ void gmlp_mfma_kernel(const ushort* __restrict__ pb,
                                 const ushort* __restrict__ WvT,
                                 const float* __restrict__ b_qkv,
                                 const ushort* __restrict__ W1T,
                                 const float* __restrict__ b_g1,
                                 const ushort* __restrict__ W2T,
                                 const float* __restrict__ b_g2,
                                 float* __restrict__ a_io) {
    __shared__ ushort Ab[64 * 200];   // 25600 B: p tile then V tile (bf16)
    __shared__ ushort Wb[192 * 72];   // 27648 B: weight chunks (two layouts)
    __shared__ ushort Hb[64 * 72];    // 9216 B: gelu hidden chunk (bf16)
    const int tid = threadIdx.x;
    const int lane = tid & 63, wave = tid >> 6;
    const int quad = lane >> 4, l16 = lane & 15;
    const int m0 = wave * 16;
    const size_t tok0 = (size_t)blockIdx.x * 64;

    // stage p tile (bf16 passthrough), 16B chunks
    for (int idx = tid * 8; idx < 64 * 192; idx += 2048) {
        int r = idx / 192, c = idx % 192;
        *(uint4*)&Ab[r * 200 + c] = *(const uint4*)&pb[(tok0 + r) * 192 + c];
    }

    // ---- v-GEMM: 64x192, K=192 ----
    f32x4 vacc[12];
#pragma unroll
    for (int i = 0; i < 12; ++i) vacc[i] = (f32x4){0.f, 0.f, 0.f, 0.f};
#pragma unroll
    for (int nc = 0; nc < 3; ++nc) {
        __syncthreads();
        for (int idx = tid * 8; idx < 64 * 192; idx += 2048) {
            int r = idx / 192, c = idx % 192;
            *(uint4*)&Wb[r * 200 + c] = *(const uint4*)&WvT[(size_t)(nc * 64 + r) * 192 + c];
        }
        __syncthreads();
#pragma unroll
        for (int kk = 0; kk < 6; ++kk) {
            bfrag a = *(const bfrag*)&Ab[(m0 + l16) * 200 + kk * 32 + quad * 8];
#pragma unroll
            for (int t = 0; t < 4; ++t) {
                bfrag b = *(const bfrag*)&Wb[(t * 16 + l16) * 200 + kk * 32 + quad * 8];
                vacc[nc * 4 + t] = __builtin_amdgcn_mfma_f32_16x16x32_bf16(
                    a, b, vacc[nc * 4 + t], 0, 0, 0);
            }
        }
    }
    // write V (bf16) into this wave's own rows of Ab
#pragma unroll
    for (int i = 0; i < 12; ++i) {
        int n = i * 16 + l16;
        float bias = b_qkv[384 + n];
#pragma unroll
        for (int reg = 0; reg < 4; ++reg) {
            int r = m0 + quad * 4 + reg;
            Ab[r * 200 + n] = f2bf(vacc[i][reg] + bias);
        }
    }

    // ---- hidden loop ----
    f32x4 acc2[12];
#pragma unroll
    for (int i = 0; i < 12; ++i) acc2[i] = (f32x4){0.f, 0.f, 0.f, 0.f};
    for (int hc = 0; hc < 12; ++hc) {
        __syncthreads();   // prior Wb reads done (also covers Ab staging/V writes)
        for (int idx = tid * 8; idx < 64 * 192; idx += 2048) {
            int r = idx / 192, c = idx % 192;
            *(uint4*)&Wb[r * 200 + c] =
                *(const uint4*)&W1T[((size_t)hc * 64 + r) * 192 + c];
        }
        __syncthreads();
        // GEMM1: H chunk 64x64, K=192
        f32x4 acc1[4];
#pragma unroll
        for (int t = 0; t < 4; ++t) acc1[t] = (f32x4){0.f, 0.f, 0.f, 0.f};
#pragma unroll
        for (int kk = 0; kk < 6; ++kk) {
            bfrag a = *(const bfrag*)&Ab[(m0 + l16) * 200 + kk * 32 + quad * 8];
#pragma unroll
            for (int t = 0; t < 4; ++t) {
                bfrag b = *(const bfrag*)&Wb[(t * 16 + l16) * 200 + kk * 32 + quad * 8];
                acc1[t] = __builtin_amdgcn_mfma_f32_16x16x32_bf16(a, b, acc1[t], 0, 0, 0);
            }
        }
        // gelu -> Hb (own-wave rows)
#pragma unroll
        for (int t = 0; t < 4; ++t) {
            int n = t * 16 + l16;
            float bb = b_g1[hc * 64 + n];
#pragma unroll
            for (int reg = 0; reg < 4; ++reg) {
                float xv = acc1[t][reg] + bb;
                Hb[(m0 + quad * 4 + reg) * 72 + n] = f2bf(gelu_erf(xv));
            }
        }
        __syncthreads();   // W1 reads done before W2 overwrite
        for (int idx = tid * 8; idx < 192 * 64; idx += 2048) {
            int r = idx / 64, c = idx % 64;
            *(uint4*)&Wb[r * 72 + c] =
                *(const uint4*)&W2T[(size_t)r * 768 + hc * 64 + c];
        }
        __syncthreads();
        // GEMM2 accumulate: 64x192, K=64
#pragma unroll
        for (int kk = 0; kk < 2; ++kk) {
            bfrag a = *(const bfrag*)&Hb[(m0 + l16) * 72 + kk * 32 + quad * 8];
#pragma unroll
            for (int t = 0; t < 12; ++t) {
                bfrag b = *(const bfrag*)&Wb[(t * 16 + l16) * 72 + kk * 32 + quad * 8];
                acc2[t] = __builtin_amdgcn_mfma_f32_16x16x32_bf16(a, b, acc2[t], 0, 0, 0);
            }
        }
    }
    // epilogue: product with attention output, in place
#pragma unroll
    for (int t = 0; t < 12; ++t) {
        int c = t * 16 + l16;
        float bg = b_g2[c];
#pragma unroll
        for (int reg = 0; reg < 4; ++reg) {
            size_t idx = (tok0 + m0 + quad * 4 + reg) * CDIM + c;
            a_io[idx] *= (acc2[t][reg] + bg);
        }
    }
}

// ---------------------------------------------------------------------------
// K7: fused = product @ w_proj + b (in-place), recon loss vs pb (bf16 target).
__launch_bounds__(256)
__global__ void proj_recon_kernel(const float* __restrict__ w_proj,
                                  const float* __restrict__ b_proj,
                                  const float* __restrict__ w_rec,
                                  const float* __restrict__ b_rec,
                                  const ushort* __restrict__ pb,
                                  float* __restrict__ a_io,
                                  float* __restrict__ loss) {
    __shared__ float T[64 * 196];
    __shared__ float WT[16 * 196];
    __shared__ float red[256];
    const int tid = threadIdx.x;
    const size_t m0 = (size_t)blockIdx.x * 64;
    const int tr = tid >> 5, tc = tid & 31;
    for (int i4 = tid * 4; i4 < 64 * 192; i4 += 1024) {
        float4 v = *(const float4*)&a_io[m0 * CDIM + i4];
        int r = i4 / 192, c = i4 - r * 192;
        *(float4*)&T[r * 196 + c] = v;
    }
    float facc[8][6] = {};
    for (int k0 = 0; k0 < 192; k0 += 16) {
        __syncthreads();
        for (int i4 = tid * 4; i4 < 16 * 192; i4 += 1024) {
            int kk = i4 / 192, c = i4 - kk * 192;
            float4 w = *(const float4*)&w_proj[(size_t)(k0 + kk) * CDIM + c];
            *(float4*)&WT[kk * 196 + c] = w;
        }
        __syncthreads();
#pragma unroll
        for (int k4 = 0; k4 < 16; k4 += 4) {
            float4 a[8];
#pragma unroll
            for (int i = 0; i < 8; ++i)
                a[i] = *(const float4*)&T[(tr + 8 * i) * 196 + k0 + k4];
#pragma unroll
            for (int kk = 0; kk < 4; ++kk) {
                float b[6];
#pragma unroll
                for (int j = 0; j < 6; ++j) b[j] = WT[(k4 + kk) * 196 + tc + 32 * j];
#pragma unroll
                for (int i = 0; i < 8; ++i) {
                    float av = (kk == 0) ? a[i].x : (kk == 1) ? a[i].y
                             : (kk == 2) ? a[i].z : a[i].w;
#pragma unroll
                    for (int j = 0; j < 6; ++j) facc[i][j] += av * b[j];
                }
            }
        }
    }
    __syncthreads();
#pragma unroll
    for (int j = 0; j < 6; ++j) {
        float bp = b_proj[tc + 32 * j];
#pragma unroll
        for (int i = 0; i < 8; ++i) {
            float fv = facc[i][j] + bp;
            T[(tr + 8 * i) * 196 + tc + 32 * j] = fv;
            a_io[(m0 + tr + 8 * i) * CDIM + tc + 32 * j] = fv;
        }
    }
    float racc[8][6] = {};
    for (int k0 = 0; k0 < 192; k0 += 16) {
        __syncthreads();
        for (int i4 = tid * 4; i4 < 16 * 192; i4 += 1024) {
            int kk = i4 / 192, c = i4 - kk * 192;
            float4 w = *(const float4*)&w_rec[(size_t)(k0 + kk) * CDIM + c];
            *(float4*)&WT[kk * 196 + c] = w;
        }
        __syncthreads();
#pragma unroll
        for (int k4 = 0; k4 < 16; k4 += 4) {
            float4 a[8];
#pragma unroll
            for (int i = 0; i < 8; ++i)
                a[i] = *(const float4*)&T[(tr + 8 * i) * 196 + k0 + k4];
#pragma unroll
            for (int kk = 0; kk < 4; ++kk) {
                float b[6];
#pragma unroll
                for (int j = 0; j < 6; ++j) b[j] = WT[(k4 + kk) * 196 + tc + 32 * j];
#pragma unroll
                for (int i = 0; i < 8; ++i) {
                    float av = (kk == 0) ? a[i].x : (kk == 1) ? a[i].y
                             : (kk == 2) ? a[i].z : a[i].w;
#pragma unroll
                    for (int j = 0; j < 6; ++j) racc[i][j] += av * b[j];
                }
            }
        }
    }
    float ls = 0.f;
#pragma unroll
    for (int j = 0; j < 6; ++j) {
        float br = b_rec[tc + 32 * j];
#pragma unroll
        for (int i = 0; i < 8; ++i) {
            float rv = racc[i][j] + br;
            ls += fabsf(rv - bf2f(pb[(m0 + tr + 8 * i) * CDIM + tc + 32 * j]));
        }
    }
    red[tid] = ls;
    __syncthreads();
    for (int s = 128; s > 0; s >>= 1) {
        if (tid < s) red[tid] += red[tid + s];
        __syncthreads();
    }
    if (tid == 0) atomicAdd(loss, red[0] * (0.1f / (float)IMGSZ));
}

// ---------------------------------------------------------------------------
// K8: window reverse + residual.
__launch_bounds__(256)
__global__ void reverse_res_kernel(const float* __restrict__ fused,
                                   const float* __restrict__ x,
                                   float* __restrict__ out) {
    __shared__ float T[CDIM][33];
    const int tid = threadIdx.x;
    const int wt = blockIdx.x, h = blockIdx.y, b = blockIdx.z;
    const int w0 = wt * 32;
    const int l = tid & 63, jo = tid >> 6;
    for (int it = 0; it < 8; ++it) {
        int j = it * 4 + jo;
        int w = w0 + j;
        size_t token = ((size_t)(b * NWH + (h >> 3)) * NWH + (w >> 3)) * TOK
                       + ((h & 7) * 8 + (w & 7));
#pragma unroll
        for (int rep = 0; rep < 3; ++rep) {
            int c = l + rep * 64;
            T[c][j] = fused[token * CDIM + c];
        }
    }
    __syncthreads();
    const size_t rowbase = (size_t)b * CDIM * HWSZ + (size_t)h * WDIM + w0;
    for (int idx = tid; idx < CDIM * 32; idx += 256) {
        int c = idx >> 5, j = idx & 31;
        size_t gp = rowbase + (size_t)c * HWSZ + j;
        out[gp] = T[c][j] + x[gp];
    }
}

// ---------------------------------------------------------------------------
extern "C" void kernel_launch(void* const* d_in, const int* in_sizes, int n_in,
                              void* d_out, int out_size, void* d_ws, size_t ws_size,
                              hipStream_t stream) {
    const float* x      = (const float*)d_in[0];
    const float* w_pre1 = (const float*)d_in[1];
    const float* b_pre1 = (const float*)d_in[2];
    const float* w_dw   = (const float*)d_in[3];
    const float* b_dw   = (const float*)d_in[4];
    const float* ln_g   = (const float*)d_in[5];
    const float* ln_b   = (const float*)d_in[6];
    const float* w_qkv  = (const float*)d_in[7];
    const float* b_qkv  = (const float*)d_in[8];
    const float* w_proj = (const float*)d_in[9];
    const float* b_proj = (const float*)d_in[10];
    const float* w_g1   = (const float*)d_in[11];
    const float* b_g1   = (const float*)d_in[12];
    const float* w_g2   = (const float*)d_in[13];
    const float* b_g2   = (const float*)d_in[14];
    const float* w_rec  = (const float*)d_in[15];
    const float* b_rec  = (const float*)d_in[16];

    float* OutR = (float*)d_out;
    float* loss = OutR + (size_t)IMGSZ;
    float* A    = (float*)d_ws;            // 154 MB fp32 region

    // d_out layout during pipeline (front->back):
    //  [f1 fp32 full]  ->  [pb bf16 77MB | bf16 weights ~0.8MB | free]
    //  final: out fp32 full + loss scalar
    ushort* pb    = (ushort*)d_out;                    // MTOK*192 bf16
    ushort* WqkvT = pb    + (size_t)MTOK * CDIM;       // 576x192 (n-major, k-contig)
    ushort* W1T   = WqkvT + 576 * 192;                 // 768x192
    ushort* W2T   = W1T   + 768 * 192;                 // 192x768
    ushort* WvT   = WqkvT + 384 * 192;                 // V rows of WqkvT (for gmlp)

    hipMemsetAsync(loss, 0, sizeof(float), stream);

    // K1: f1 = conv1x1(x) -> d_out (fp32)
    conv1x1_kernel<<<dim3(HWSZ / 64, CDIM / 64, BATCH), 256, 0, stream>>>(
        x, w_pre1, b_pre1, OutR);
    // K2: f2 = dwconv(f1) -> A
    dwconv_kernel<<<IMGSZ / 256, 256, 0, stream>>>(OutR, w_dw, b_dw, A);
    // prep bf16 weights (after f1 is dead)
    prep_weights_kernel<<<(768 * 192 + 255) / 256, 256, 0, stream>>>(
        w_qkv, w_g1, w_g2, WqkvT, W1T, W2T);
    // K3: pb = LN+partition(f2) -> d_out front (bf16)
    ln_part_kernel<<<dim3(WDIM / 32, HDIM, BATCH), 256, 0, stream>>>(
        A, ln_g, ln_b, pb);
    // K4: MFMA attention -> A
    attn_mfma_kernel<<<NWIN, 256, 0, stream>>>(pb, WqkvT, b_qkv, A);
    // K5: A = attn .* gmlp(v) in place (MFMA)
    gmlp_mfma_kernel<<<MTOK / 64, 256, 0, stream>>>(
        pb, WvT, b_qkv, W1T, b_g1, W2T, b_g2, A);
    // K7: A = product @ w_proj + b (in place); recon loss vs pb
    proj_recon_kernel<<<MTOK / 64, 256, 0, stream>>>(
        w_proj, b_proj, w_rec, b_rec, pb, A, loss);
    // K8: out = reverse(A) + x -> d_out
    reverse_res_kernel<<<dim3(WDIM / 32, HDIM, BATCH), 256, 0, stream>>>(
        A, x, OutR);
}